// Round 1
// 331.222 us; speedup vs baseline: 1.0468x; 1.0468x over previous
//
#include <hip/hip_runtime.h>
#include <cstdint>
#include <cstddef>

// ---- problem constants ----
#define BN_   16
#define C_    480
#define T_    8
#define FY_   28
#define FX_   28
#define NDF_  256
#define KC_   64
#define M_    1024            // BN*SN rows
#define KD_   30720           // C*8*8
#define PLANE_ 784
#define CHSTRIDE_ (T_*PLANE_) // 6272 floats between channels
#define CT_   (C_*CHSTRIDE_)  // per-bn stride
#define KS_   32              // split-K factor
#define KCH_  960             // K per split (15 whole channels)
#define NCH_  15              // channels per split
#define NSTEP_ 30             // K-steps per split (BK=32)
#define MT_   64              // M-tile (rois per block) -- one full bn image
#define AOS_  520             // A LDS octet stride in ushorts (1040 B; %32 words = 4 -> bank rotate)
#define BTILE_ 16384          // ushorts per packed step-tile (hi 8192 + lo 8192)

typedef __attribute__((ext_vector_type(8))) short bf16x8;
typedef __attribute__((ext_vector_type(4))) float f32x4;

__device__ __forceinline__ unsigned rne_bf16(float f) {
    union { float f; unsigned u; } v; v.f = f;
    return v.u + 0x7FFFu + ((v.u >> 16) & 1u);   // RNE; bf16 bits = result >> 16
}
__device__ __forceinline__ float bfbits_to_f(unsigned r) {
    union { unsigned u; float f; } v; v.u = r & 0xFFFF0000u;
    return v.f;
}
__device__ __forceinline__ void lds_dma16(const void* g, void* l) {
    __builtin_amdgcn_global_load_lds((const __attribute__((address_space(1))) void*)g,
                                     (__attribute__((address_space(3))) void*)l, 16, 0, 0);
}

// ---------------------------------------------------------------------------
// Kernel 1: pack W into per-step tiles in CONFLICT-FREE octet-major layout:
// tile(ks*30+s) = hi[oct(4)][n(256)][8 ushorts] ++ lo[same].
// element (n,k): hi[(k>>3)*2048 + n*8 + (k&7)].  Reads & writes coalesced.
// ---------------------------------------------------------------------------
__global__ __launch_bounds__(256)
void convert_pack(const float* __restrict__ W, unsigned short* __restrict__ Bpack) {
    const int blk = blockIdx.x;              // 0..959 = ks*30 + s
    const int kb = blk * 32;                 // global k base
    const int n = threadIdx.x;
    unsigned hw[16], lw[16];
    #pragma unroll
    for (int p = 0; p < 16; ++p) {           // k-pair (2p, 2p+1)
        const float v0 = W[(size_t)(kb + 2 * p) * NDF_ + n];
        const float v1 = W[(size_t)(kb + 2 * p + 1) * NDF_ + n];
        const unsigned h0 = rne_bf16(v0), h1 = rne_bf16(v1);
        const unsigned l0 = rne_bf16(v0 - bfbits_to_f(h0));
        const unsigned l1 = rne_bf16(v1 - bfbits_to_f(h1));
        hw[p] = __builtin_amdgcn_perm(h1, h0, 0x07060302u);  // lo16 = even k
        lw[p] = __builtin_amdgcn_perm(l1, l0, 0x07060302u);
    }
    uint4* hb4 = (uint4*)(Bpack + (size_t)blk * BTILE_);     // hi: 1024 uint4
    uint4* lb4 = hb4 + 1024;                                 // lo
    #pragma unroll
    for (int o = 0; o < 4; ++o) {            // octet o = k 8o..8o+7 -> uint4 idx o*256+n
        hb4[o * 256 + n] = make_uint4(hw[o * 4 + 0], hw[o * 4 + 1], hw[o * 4 + 2], hw[o * 4 + 3]);
        lb4[o * 256 + n] = make_uint4(lw[o * 4 + 0], lw[o * 4 + 1], lw[o * 4 + 2], lw[o * 4 + 3]);
    }
}

// ---------------------------------------------------------------------------
// Kernel 2: cent [64][256] -> centT [256][64] fp32
// ---------------------------------------------------------------------------
__global__ void convert_cent(const float* __restrict__ cent, float* __restrict__ centT) {
    const int k = blockIdx.x;
    const int j = threadIdx.x;
    centT[(size_t)j * KC_ + k] = cent[(size_t)k * NDF_ + j];
}

// ---------------------------------------------------------------------------
// Kernel 3: fused ROI-align + split-bf16 (3-product) MFMA split-K GEMM.
// R9: atomic epilogue replaced by per-split partial stores (z_part[ks]).
// Device-scope f32 atomics were memory-side RMWs (WRITE_SIZE == 8.4M*4B);
// plain coalesced stores + a 32-way fold in cluster_kernel instead.
// ---------------------------------------------------------------------------
__global__ __launch_bounds__(256, 2)
void gemm_fused(const float* __restrict__ z_vis, const unsigned short* __restrict__ Bpack,
                const float* __restrict__ bboxs, float* __restrict__ z_part) {
    __shared__ short Ah[8 * AOS_];           // 8.3 KB  [oct][m][8]
    __shared__ short Al[8 * AOS_];           // 8.3 KB
    __shared__ unsigned short Bh[8192];      // 16 KB   [oct(4)][n(256)][8]
    __shared__ unsigned short Bl[8192];      // 16 KB
    __shared__ float Pl[PLANE_];             // 3.1 KB  current channel plane

    const int t = threadIdx.x;
    const int ks = blockIdx.x, mi = blockIdx.y;   // mi == bn
    const int lane = t & 63, wid = t >> 6;

    // ---- A-gen assignment: m = t>>2 (0..63); by-pair {t&3, (t&3)+4} ----
    const int m = t >> 2, byl = t & 3;
    const int roi = mi * MT_ + m;

    // kernel-lifetime sampling constants
    int xi0[8], xi1[8];
    float xw0[8], xw1[8];
    int yr0[2], yr1[2];
    float wy0[2], wy1[2];
    {
        const float bx1 = bboxs[roi * 4 + 0], by1 = bboxs[roi * 4 + 1];
        const float bx2 = bboxs[roi * 4 + 2], by2 = bboxs[roi * 4 + 3];
        const float sx = 28.0f / 1920.0f, sy = 28.0f / 1080.0f;
        const float lo_x = bx1 * sx - 0.5f;
        const float binw_x = (bx2 * sx - 0.5f - lo_x) * 0.125f;
        const float lo_y = by1 * sy - 0.5f;
        const float binw_y = (by2 * sy - 0.5f - lo_y) * 0.125f;
        #pragma unroll
        for (int b = 0; b < 8; ++b) {
            const float pos = lo_x + ((float)b + 0.5f) * binw_x;
            const float vx = (pos > -1.0f && pos < 28.0f) ? 1.0f : 0.0f;
            const float pc = fminf(fmaxf(pos, 0.0f), 27.0f);
            const float p0 = floorf(pc);
            const float lx = pc - p0;
            xi0[b] = (int)p0;
            xi1[b] = min(xi0[b] + 1, 27);
            xw0[b] = vx * (1.0f - lx);
            xw1[b] = vx * lx;
        }
        #pragma unroll
        for (int h = 0; h < 2; ++h) {
            const int by = byl + h * 4;
            const float pos = lo_y + ((float)by + 0.5f) * binw_y;
            const float vy = (pos > -1.0f && pos < 28.0f) ? 1.0f : 0.0f;
            const float pc = fminf(fmaxf(pos, 0.0f), 27.0f);
            const float p0 = floorf(pc);
            const float ly = pc - p0;
            const int y0 = (int)p0, y1 = min(y0 + 1, 27);
            yr0[h] = y0 * FX_; yr1[h] = y1 * FX_;
            wy0[h] = vy * (1.0f - ly); wy1[h] = vy * ly;
        }
    }
    const float* plane = z_vis + (size_t)mi * CT_ + (size_t)(T_ - 1) * PLANE_;

    // ---- plane DMA: 4 waves cover 3136 B (wave3: 4 lanes) ----
    auto plane_load = [&](int cc) {
        const char* gb = (const char*)(plane + (size_t)(ks * NCH_ + cc) * CHSTRIDE_);
        if (wid < 3) {
            lds_dma16(gb + (wid * 64 + lane) * 16, (char*)Pl + wid * 1024);
        } else if (lane < 4) {
            lds_dma16(gb + (192 + lane) * 16, (char*)Pl + 3072);
        }
    };

    // ---- B staging: contiguous 16 KB hi + 16 KB lo; layout == LDS ----
    auto stage_B = [&](int s) {
        const char* hb = (const char*)(Bpack + (size_t)(ks * NSTEP_ + s) * BTILE_);
        #pragma unroll
        for (int qq = 0; qq < 4; ++qq) {
            const int chunk = (qq * 4 + wid) * 1024;        // wave-uniform byte offset
            lds_dma16(hb + chunk + lane * 16, (char*)Bh + chunk);
            lds_dma16(hb + 16384 + chunk + lane * 16, (char*)Bl + chunk);
        }
    };

    // ---- A-gen: one channel (64 k) from LDS plane; 2 octets per thread ----
    auto stage_A = [&]() {
        #pragma unroll
        for (int h = 0; h < 2; ++h) {
            const int by = byl + h * 4;                     // octet index
            const int r0 = yr0[h], r1 = yr1[h];
            const float w0 = wy0[h], w1 = wy1[h];
            unsigned rh[8], rl[8];
            #pragma unroll
            for (int b = 0; b < 8; ++b) {
                const float v00 = Pl[r0 + xi0[b]], v01 = Pl[r0 + xi1[b]];
                const float v10 = Pl[r1 + xi0[b]], v11 = Pl[r1 + xi1[b]];
                const float val = w0 * (xw0[b] * v00 + xw1[b] * v01)
                                + w1 * (xw0[b] * v10 + xw1[b] * v11);
                rh[b] = rne_bf16(val);
                rl[b] = rne_bf16(val - bfbits_to_f(rh[b]));
            }
            const uint4 hh = make_uint4(__builtin_amdgcn_perm(rh[1], rh[0], 0x07060302u),
                                        __builtin_amdgcn_perm(rh[3], rh[2], 0x07060302u),
                                        __builtin_amdgcn_perm(rh[5], rh[4], 0x07060302u),
                                        __builtin_amdgcn_perm(rh[7], rh[6], 0x07060302u));
            const uint4 ll = make_uint4(__builtin_amdgcn_perm(rl[1], rl[0], 0x07060302u),
                                        __builtin_amdgcn_perm(rl[3], rl[2], 0x07060302u),
                                        __builtin_amdgcn_perm(rl[5], rl[4], 0x07060302u),
                                        __builtin_amdgcn_perm(rl[7], rl[6], 0x07060302u));
            *(uint4*)&Ah[by * AOS_ + m * 8] = hh;
            *(uint4*)&Al[by * AOS_ + m * 8] = ll;
        }
    };

    const int fr = lane & 15, fq = lane >> 4;
    f32x4 acc[4][4] = {};

    // ---- prologue ----
    plane_load(0);
    stage_B(0);
    __syncthreads();                         // plane(0)+B(0) landed
    stage_A();                               // A(ch 0)

    for (int cc = 0; cc < NCH_; ++cc) {
        #pragma unroll
        for (int half = 0; half < 2; ++half) {
            const int s = 2 * cc + half;
            __syncthreads();                 // A written / B(s)+plane landed

            // ---- fragments -> registers (conflict-free octet-major) ----
            bf16x8 afh[4], afl[4], bh[4], bl[4];
            #pragma unroll
            for (int i = 0; i < 4; ++i) {
                const int ao = (half * 4 + fq) * AOS_ + (i * 16 + fr) * 8;
                afh[i] = *(const bf16x8*)&Ah[ao];
                afl[i] = *(const bf16x8*)&Al[ao];
            }
            #pragma unroll
            for (int j = 0; j < 4; ++j) {
                const int bo = fq * 2048 + (wid * 64 + j * 16 + fr) * 8;
                bh[j] = *(const bf16x8*)&Bh[bo];
                bl[j] = *(const bf16x8*)&Bl[bo];
            }
            __syncthreads();                 // reads done; LDS reusable

            if (half == 0) {
                stage_B(s + 1);
                if (cc + 1 < NCH_) plane_load(cc + 1);
            } else if (cc + 1 < NCH_) {
                stage_B(s + 1);
                stage_A();                   // A(ch cc+1); plane landed earlier
            }

            #pragma unroll
            for (int j = 0; j < 4; ++j)
                #pragma unroll
                for (int i = 0; i < 4; ++i) {
                    acc[i][j] = __builtin_amdgcn_mfma_f32_16x16x32_bf16(afh[i], bh[j], acc[i][j], 0, 0, 0);
                    acc[i][j] = __builtin_amdgcn_mfma_f32_16x16x32_bf16(afl[i], bh[j], acc[i][j], 0, 0, 0);
                    acc[i][j] = __builtin_amdgcn_mfma_f32_16x16x32_bf16(afh[i], bl[j], acc[i][j], 0, 0, 0);
                }
        }
    }

    // ---- store split partial (C/D: col=lane&15, row=(lane>>4)*4+r) ----
    // Plain coalesced stores to a private per-split slice; no atomics.
    float* zp = z_part + (size_t)ks * (M_ * NDF_);
    #pragma unroll
    for (int i = 0; i < 4; ++i) {
        const int row = mi * MT_ + i * 16 + fq * 4;
        #pragma unroll
        for (int j = 0; j < 4; ++j) {
            const int col = wid * 64 + j * 16 + fr;
            #pragma unroll
            for (int r = 0; r < 4; ++r)
                zp[(size_t)(row + r) * NDF_ + col] = acc[i][j][r];
        }
    }
}

// ---------------------------------------------------------------------------
// Kernel 4: fold split-K partials + spatial term + soft-assignment clustering.
// ---------------------------------------------------------------------------
__global__ __launch_bounds__(256)
void cluster_kernel(const float* __restrict__ z_part, const float* __restrict__ bboxs,
                    const float* __restrict__ b_vis, const float* __restrict__ W_spc,
                    const float* __restrict__ b_spc, const float* __restrict__ centT,
                    float* __restrict__ out) {
    const int row = blockIdx.x, t = threadIdx.x;
    __shared__ float zs[NDF_];
    __shared__ float dp[4][KC_];

    // fold 32 split-K partials (coalesced: consecutive t -> consecutive addrs)
    float a = 0.0f;
    const float* zp = z_part + (size_t)row * NDF_ + t;
    #pragma unroll
    for (int s = 0; s < KS_; ++s)
        a += zp[(size_t)s * (M_ * NDF_)];

    const float x1 = bboxs[row * 4 + 0], y1 = bboxs[row * 4 + 1];
    const float x2 = bboxs[row * 4 + 2], y2 = bboxs[row * 4 + 3];
    const float cx = x1 + (x2 - x1) * 0.5f - 960.0f;
    const float cy = y1 + (y2 - y1) * 0.5f - 540.0f;
    const float nrm = sqrtf(cx * cx + cy * cy) / sqrtf(960.0f * 960.0f + 540.0f * 540.0f);

    const float zj = a + b_vis[t] + nrm * W_spc[t] + b_spc[t];
    zs[t] = zj;
    out[(size_t)row * NDF_ + t] = zj;                         // output 0: z
    __syncthreads();

    const int k = t & 63, qq = t >> 6;
    {
        float d2 = 0.0f;
        const float* ct = centT + (size_t)qq * 64 * KC_;
        #pragma unroll 8
        for (int j = 0; j < 64; ++j) {
            const float df = zs[qq * 64 + j] - ct[(size_t)j * KC_ + k];
            d2 += df * df;
        }
        dp[qq][k] = d2;
    }
    __syncthreads();

    if (t < 64) {
        const float d = sqrtf(dp[0][t] + dp[1][t] + dp[2][t] + dp[3][t]);
        const float su = 1.0f / (1.0f + d);                   // ALPHA=1
        float sum = su;
        #pragma unroll
        for (int mk = 1; mk < 64; mk <<= 1) sum += __shfl_xor(sum, mk, 64);
        out[(size_t)M_ * NDF_ + (size_t)row * KC_ + t] = su / sum;   // output 1: s
        float v = d; int idx = t;
        #pragma unroll
        for (int mk = 1; mk < 64; mk <<= 1) {
            const float ov = __shfl_xor(v, mk, 64);
            const int oi = __shfl_xor(idx, mk, 64);
            if (ov < v || (ov == v && oi < idx)) { v = ov; idx = oi; }
        }
        if (t == 0)
            out[(size_t)M_ * NDF_ + (size_t)M_ * KC_ + row] = (float)idx;  // output 2: c
    }
}

// ---------------------------------------------------------------------------
extern "C" void kernel_launch(void* const* d_in, const int* in_sizes, int n_in,
                              void* d_out, int out_size, void* d_ws, size_t ws_size,
                              hipStream_t stream) {
    const float* z_vis = (const float*)d_in[0];
    const float* bboxs = (const float*)d_in[1];
    const float* W_vis = (const float*)d_in[2];
    const float* b_vis = (const float*)d_in[3];
    const float* W_spc = (const float*)d_in[4];
    const float* b_spc = (const float*)d_in[5];
    const float* cent  = (const float*)d_in[6];
    float* out = (float*)d_out;

    char* ws = (char*)d_ws;
    unsigned short* Bpack = (unsigned short*)ws;                 // 960*32768 = 31,457,280 B
    float*          centT = (float*)(ws + 31457280);             //     65,536 B
    float*          z_part = (float*)(ws + 31457280 + 65536);    // 32*1 MB = 33,554,432 B
    // total ws: ~62.1 MB

    convert_pack<<<KS_ * NSTEP_, 256, 0, stream>>>(W_vis, Bpack);
    convert_cent<<<KC_, 256, 0, stream>>>(cent, centT);
    gemm_fused<<<dim3(KS_, M_ / MT_), 256, 0, stream>>>(z_vis, Bpack, bboxs, z_part);
    cluster_kernel<<<M_, 256, 0, stream>>>(z_part, bboxs, b_vis, W_spc, b_spc, centT, out);
}